// Round 1
// baseline (200.372 us; speedup 1.0000x reference)
//
#include <hip/hip_runtime.h>

#define NTOK 32768
#define D 1024
#define NE 8

// ---- cross-lane helpers ------------------------------------------------
// DPP row_ror rotate-reduce: after steps 1,2,4,8 every lane in a 16-lane row
// holds the row sum. VALU pipe (cheap) vs shfl (LDS pipe).
template<int CTRL>
__device__ __forceinline__ float dpp_row_add(float v) {
    int r = __builtin_amdgcn_update_dpp(0, __float_as_int(v), CTRL, 0xf, 0xf, true);
    return v + __int_as_float(r);
}

__device__ __forceinline__ float row_reduce_add(float v) {
    v = dpp_row_add<0x121>(v);  // row_ror:1
    v = dpp_row_add<0x122>(v);  // row_ror:2
    v = dpp_row_add<0x124>(v);  // row_ror:4
    v = dpp_row_add<0x128>(v);  // row_ror:8
    return v;                   // all 16 lanes of each row hold the row sum
}

__device__ __forceinline__ float wave_reduce_add(float v) {
    v = row_reduce_add(v);
    v += __shfl_xor(v, 16, 64);
    v += __shfl_xor(v, 32, 64);
    return v;                   // all 64 lanes hold the wave sum
}

// ---- kernel 1: logits = x @ W^T  (memory-streaming, wave per token) ----
// Lane l owns d in {4l + 256c : c=0..3}. W stays resident in 128 VGPRs.
__global__ __launch_bounds__(256, 2) void logits_kernel(
        const float* __restrict__ x, const float* __restrict__ W,
        float* __restrict__ logits) {
    const int lane = threadIdx.x & 63;
    const int wid  = (blockIdx.x * blockDim.x + threadIdx.x) >> 6;
    const int nw   = (gridDim.x * blockDim.x) >> 6;

    float4 w[NE][4];
#pragma unroll
    for (int e = 0; e < NE; ++e)
#pragma unroll
        for (int c = 0; c < 4; ++c)
            w[e][c] = *(const float4*)(W + e * D + c * 256 + lane * 4);

    int t = wid;
    float4 xq[4];
    if (t < NTOK) {
        const float* xr = x + (size_t)t * D + lane * 4;
#pragma unroll
        for (int c = 0; c < 4; ++c) xq[c] = *(const float4*)(xr + c * 256);
    }

    while (t < NTOK) {
        // software-prefetch next token's x while computing current
        const int tn = t + nw;
        float4 xn[4];
        if (tn < NTOK) {
            const float* xr = x + (size_t)tn * D + lane * 4;
#pragma unroll
            for (int c = 0; c < 4; ++c) xn[c] = *(const float4*)(xr + c * 256);
        }

        float acc[NE];
#pragma unroll
        for (int e = 0; e < NE; ++e) {
            float s = 0.f;
#pragma unroll
            for (int c = 0; c < 4; ++c) {
                s = fmaf(xq[c].x, w[e][c].x, s);
                s = fmaf(xq[c].y, w[e][c].y, s);
                s = fmaf(xq[c].z, w[e][c].z, s);
                s = fmaf(xq[c].w, w[e][c].w, s);
            }
            acc[e] = row_reduce_add(s);   // per-row partial, all 8 experts
        }

        // lane picks expert (lane&7)'s row-partial, then sums the 4 rows
        const int k = lane & 7;
        float b0 = (k & 1) ? acc[1] : acc[0];
        float b1 = (k & 1) ? acc[3] : acc[2];
        float b2 = (k & 1) ? acc[5] : acc[4];
        float b3 = (k & 1) ? acc[7] : acc[6];
        float c0 = (k & 2) ? b1 : b0;
        float c1 = (k & 2) ? b3 : b2;
        float v  = (k & 4) ? c1 : c0;
        v += __shfl_xor(v, 16, 64);
        v += __shfl_xor(v, 32, 64);       // v = logit[lane&7], every lane

        if (lane < NE) logits[t * NE + lane] = v;

        t = tn;
#pragma unroll
        for (int c = 0; c < 4; ++c) xq[c] = xn[c];
    }
}

// ---- kernel 2: softmax / top-2 / per-token stats (thread per token) ----
// ws layout: [0..7] sum of probs per expert, [8..15] token counts, [16] entropy sum
__global__ __launch_bounds__(256) void router_kernel(
        const float* __restrict__ logits, float* __restrict__ dw,
        float* __restrict__ eidx, float* __restrict__ ws) {
    __shared__ float s_acc[17];
    const int tid = threadIdx.x;
    if (tid < 17) s_acc[tid] = 0.f;
    __syncthreads();

    const int t = blockIdx.x * 256 + tid;
    float l[8];
    const float4 a = *(const float4*)(logits + t * 8);
    const float4 b = *(const float4*)(logits + t * 8 + 4);
    l[0] = a.x; l[1] = a.y; l[2] = a.z; l[3] = a.w;
    l[4] = b.x; l[5] = b.y; l[6] = b.z; l[7] = b.w;

    float m = l[0];
#pragma unroll
    for (int e = 1; e < 8; ++e) m = fmaxf(m, l[e]);
    float p[8], S = 0.f;
#pragma unroll
    for (int e = 0; e < 8; ++e) { p[e] = __expf(l[e] - m); S += p[e]; }
    const float inv = 1.0f / S;
#pragma unroll
    for (int e = 0; e < 8; ++e) p[e] *= inv;

    // top-2, strict > keeps lowest index on ties (matches jax.lax.top_k)
    int e1 = 0; float p1 = p[0];
#pragma unroll
    for (int e = 1; e < 8; ++e) if (p[e] > p1) { p1 = p[e]; e1 = e; }
    int e2 = -1; float p2 = -1.f;
#pragma unroll
    for (int e = 0; e < 8; ++e) if (e != e1 && p[e] > p2) { p2 = p[e]; e2 = e; }

    dw[t * 2 + 0]   = p1;
    dw[t * 2 + 1]   = p2;
    eidx[t * 2 + 0] = (float)e1;
    eidx[t * 2 + 1] = (float)e2;

    const float logS = __logf(S);
    float ent = 0.f;
#pragma unroll
    for (int e = 0; e < 8; ++e) ent -= p[e] * (l[e] - m - logS);

    // wave-level reductions (VALU DPP + 2 shfl each), then LDS, then global
    const bool lead = ((tid & 63) == 0);
#pragma unroll
    for (int e = 0; e < 8; ++e) {
        float r = wave_reduce_add(p[e]);
        if (lead) atomicAdd(&s_acc[e], r);
    }
#pragma unroll
    for (int e = 0; e < 8; ++e) {
        float r = wave_reduce_add((float)((e1 == e) + (e2 == e)));
        if (lead) atomicAdd(&s_acc[8 + e], r);
    }
    {
        float r = wave_reduce_add(ent);
        if (lead) atomicAdd(&s_acc[16], r);
    }
    __syncthreads();
    if (tid < 17) atomicAdd(&ws[tid], s_acc[tid]);
}

// ---- kernel 3: finalize scalars ----------------------------------------
// scalars layout in d_out tail: [0] load_balance_loss, [1] entropy_loss,
// [2] num_dropped, [3..10] expert_usage
__global__ void finalize_kernel(const float* __restrict__ ws,
                                float* __restrict__ outs) {
    if (threadIdx.x == 0 && blockIdx.x == 0) {
        const float invN = 1.0f / 32768.0f;
        float lbl = 0.f, dropped = 0.f;
#pragma unroll
        for (int e = 0; e < 8; ++e) {
            const float cnt = ws[8 + e];
            const float avg = ws[e] * invN;       // avg_probs
            lbl += (cnt * invN) * avg;
            if (cnt > 10240.0f) dropped += 1.f;   // per_expert_capacity = 81920/8
            outs[3 + e] = cnt * invN;             // expert_usage
        }
        outs[0] = lbl * 8.0f;
        const float ent = ws[16] * invN;
        outs[1] = fmaxf(2.0794415416798357f - ent, 0.0f);  // log(8) - entropy
        outs[2] = dropped;
    }
}

extern "C" void kernel_launch(void* const* d_in, const int* in_sizes, int n_in,
                              void* d_out, int out_size, void* d_ws, size_t ws_size,
                              hipStream_t stream) {
    const float* x = (const float*)d_in[0];
    const float* W = (const float*)d_in[1];
    float* out     = (float*)d_out;

    // output layout (flat concat, everything as fp32):
    float* dw      = out;            // [32768,2] dispatch_weights
    float* eidx    = out + 65536;    // [32768,2] expert_indices (as float)
    float* logits  = out + 131072;   // [32768,8] router_logits
    float* scalars = out + 393216;   // lbl, ent_loss, num_dropped, usage[8]
    float* ws      = (float*)d_ws;   // 17 accumulators

    hipMemsetAsync(d_ws, 0, 32 * sizeof(float), stream);
    logits_kernel<<<512, 256, 0, stream>>>(x, W, logits);
    router_kernel<<<128, 256, 0, stream>>>(logits, dw, eidx, ws);
    finalize_kernel<<<1, 64, 0, stream>>>(ws, scalars);
}

// Round 3
// 199.322 us; speedup vs baseline: 1.0053x; 1.0053x over previous
//
#include <hip/hip_runtime.h>

#define NTOK 32768
#define D 1024
#define NE 8
#define NWAVES 2048   // 512 blocks * 4 waves

// ---- cross-lane helpers ------------------------------------------------
// DPP row_ror rotate: lane gets value from (lane + k) within its 16-lane
// row. VALU pipe (free-ish) vs shfl (LDS pipe).
template<int CTRL>
__device__ __forceinline__ float dpp_ror(float v) {
    return __int_as_float(
        __builtin_amdgcn_update_dpp(0, __float_as_int(v), CTRL, 0xf, 0xf, true));
}

// sum over each 16-lane row (all lanes get row sum)
__device__ __forceinline__ float row_reduce_add(float v) {
    v += dpp_ror<0x121>(v);
    v += dpp_ror<0x122>(v);
    v += dpp_ror<0x124>(v);
    v += dpp_ror<0x128>(v);
    return v;
}

__device__ __forceinline__ float wave_reduce_add(float v) {
    v = row_reduce_add(v);
    v += __shfl_xor(v, 16, 64);
    v += __shfl_xor(v, 32, 64);
    return v;
}

// For period-8-replicated values: sum / max over the 8 distinct entries,
// entirely on the VALU (DPP) pipe. Valid because v(lane) depends only on
// lane&7, so row rotations by 1/2/4 hit the 8 distinct values exactly once.
__device__ __forceinline__ float grp8_add(float v) {
    v += dpp_ror<0x121>(v);
    v += dpp_ror<0x122>(v);
    v += dpp_ror<0x124>(v);
    return v;
}
__device__ __forceinline__ float grp8_max(float v) {
    v = fmaxf(v, dpp_ror<0x121>(v));
    v = fmaxf(v, dpp_ror<0x122>(v));
    v = fmaxf(v, dpp_ror<0x124>(v));
    return v;
}
// sum over lanes sharing (lane&7): ror:8 within a 16-row == xor 8
__device__ __forceinline__ float red_per_expert(float v) {
    v += dpp_ror<0x128>(v);
    v += __shfl_xor(v, 16, 64);
    v += __shfl_xor(v, 32, 64);
    return v;   // lane l holds sum over all 8 lanes with same (l&7)
}

// ---- kernel 1: fused logits + softmax + top-2 + stats ------------------
// Wave per token-iteration. Lane l owns d in {4l + 256c : c=0..3}; W stays
// resident in 128 VGPRs. Per-wave stats go to private ws slots (no atomics,
// no zero-init needed).
//
// REPLICATION NOTE: all 64 lanes of a wave process the SAME token, and the
// per-token quantities (p, counts) depend only on lane&7 — so per-expert
// accumulators are replicated 8x across the wave. red_per_expert sums the
// 8 copies; the final per-wave partials must be scaled by 1/8. (R2 bug:
// missing scale made load_balance_loss 64x too big — error 126. Entropy
// uses wave_reduce_add over 8 copies of the 8-expert sum -> -1/8 scale.)
__global__ __launch_bounds__(256, 2) void fused_kernel(
        const float* __restrict__ x, const float* __restrict__ W,
        float* __restrict__ logits, float* __restrict__ dw,
        float* __restrict__ eidx, float* __restrict__ ws) {
    const int lane = threadIdx.x & 63;
    const int wid  = (blockIdx.x * blockDim.x + threadIdx.x) >> 6;
    const int nw   = (gridDim.x * blockDim.x) >> 6;
    const int k    = lane & 7;

    float4 w[NE][4];
#pragma unroll
    for (int e = 0; e < NE; ++e)
#pragma unroll
        for (int c = 0; c < 4; ++c)
            w[e][c] = *(const float4*)(W + e * D + c * 256 + lane * 4);

    float p_acc = 0.f, c_acc = 0.f, ent_acc = 0.f;

    int t = wid;
    float4 xq[4];
    if (t < NTOK) {
        const float* xr = x + (size_t)t * D + lane * 4;
#pragma unroll
        for (int c = 0; c < 4; ++c) xq[c] = *(const float4*)(xr + c * 256);
    }

    while (t < NTOK) {
        // software-prefetch next token's x while computing current
        const int tn = t + nw;
        float4 xn[4];
        if (tn < NTOK) {
            const float* xr = x + (size_t)tn * D + lane * 4;
#pragma unroll
            for (int c = 0; c < 4; ++c) xn[c] = *(const float4*)(xr + c * 256);
        }

        // ---- dot products: acc[e] = per-16-row partial sums ----
        float acc[NE];
#pragma unroll
        for (int e = 0; e < NE; ++e) {
            float s = 0.f;
#pragma unroll
            for (int c = 0; c < 4; ++c) {
                s = fmaf(xq[c].x, w[e][c].x, s);
                s = fmaf(xq[c].y, w[e][c].y, s);
                s = fmaf(xq[c].z, w[e][c].z, s);
                s = fmaf(xq[c].w, w[e][c].w, s);
            }
            acc[e] = row_reduce_add(s);
        }

        // lane picks expert (lane&7)'s row-partial, sums the 4 rows
        float b0 = (k & 1) ? acc[1] : acc[0];
        float b1 = (k & 1) ? acc[3] : acc[2];
        float b2 = (k & 1) ? acc[5] : acc[4];
        float b3 = (k & 1) ? acc[7] : acc[6];
        float c0 = (k & 2) ? b1 : b0;
        float c1 = (k & 2) ? b3 : b2;
        float v  = (k & 4) ? c1 : c0;
        v += __shfl_xor(v, 16, 64);
        v += __shfl_xor(v, 32, 64);   // v = logit[lane&7], replicated wave-wide

        // ---- softmax over the 8 experts (all DPP, fully replicated) ----
        const float m    = grp8_max(v);
        const float pe   = __expf(v - m);
        const float S    = grp8_add(pe);
        const float p    = pe / S;
        const float logS = __logf(S);

        // ---- top-2, lowest index wins ties ----
        const float m1 = grp8_max(p);
        const unsigned long long b1m = __ballot(p == m1);
        const int e1 = __ffsll(b1m & 0xffull) - 1;
        const float cand = (k == e1) ? -1.0f : p;
        const float m2 = grp8_max(cand);
        const unsigned long long b2m = __ballot(cand == m2);
        const int e2 = __ffsll(b2m & 0xffull) - 1;

        // ---- outputs ----
        if (lane < 8)       logits[t * 8 + lane] = v;
        if (lane == 0)      *(float2*)(dw   + t * 2) = make_float2(m1, m2);
        else if (lane == 1) *(float2*)(eidx + t * 2) = make_float2((float)e1, (float)e2);

        // ---- stats (accumulate per-lane, reduce once per wave at end) ----
        p_acc   += p;
        c_acc   += (float)((k == e1) + (k == e2));
        ent_acc += p * (v - m - logS);   // = p * log p  (negative)

        t = tn;
#pragma unroll
        for (int c = 0; c < 4; ++c) xq[c] = xn[c];
    }

    // per-wave partials -> private ws slot. 0.125f undoes the 8x wave
    // replication (see REPLICATION NOTE above).
    const float pr = red_per_expert(p_acc) * 0.125f;  // lane l: expert l&7 prob sum
    const float cr = red_per_expert(c_acc) * 0.125f;  // lane l: expert l&7 count
    const float er = wave_reduce_add(ent_acc) * -0.125f;  // entropy sum
    const float outv = (lane < 8) ? pr : ((lane < 16) ? cr : er);
    if (lane < 17) ws[wid * 17 + lane] = outv;
}

// ---- kernel 2: reduce 2048x17 partials, emit scalars -------------------
// out tail: [0] load_balance_loss, [1] entropy_loss, [2] num_dropped,
// [3..10] expert_usage
__global__ __launch_bounds__(256) void finalize_kernel(
        const float* __restrict__ ws, float* __restrict__ outs) {
    __shared__ float s_acc[17];
    const int tid = threadIdx.x;
    if (tid < 17) s_acc[tid] = 0.f;
    __syncthreads();

    float loc[17];
#pragma unroll
    for (int i = 0; i < 17; ++i) loc[i] = 0.f;
    for (int w = tid; w < NWAVES; w += 256) {
        const float* p = ws + w * 17;
#pragma unroll
        for (int i = 0; i < 17; ++i) loc[i] += p[i];
    }
#pragma unroll
    for (int i = 0; i < 17; ++i) {
        const float r = wave_reduce_add(loc[i]);
        if ((tid & 63) == 0) atomicAdd(&s_acc[i], r);
    }
    __syncthreads();

    if (tid == 0) {
        const float invN = 1.0f / 32768.0f;
        float lbl = 0.f, dropped = 0.f;
#pragma unroll
        for (int e = 0; e < 8; ++e) {
            const float cnt = s_acc[8 + e];
            lbl += (cnt * invN) * (s_acc[e] * invN);
            if (cnt > 10240.0f) dropped += 1.f;    // capacity = 32768*2*1.25/8
            outs[3 + e] = cnt * invN;              // expert_usage
        }
        outs[0] = lbl * 8.0f;
        const float ent = s_acc[16] * invN;
        outs[1] = fmaxf(2.0794415416798357f - ent, 0.0f);   // log(8) - entropy
        outs[2] = dropped;
    }
}

extern "C" void kernel_launch(void* const* d_in, const int* in_sizes, int n_in,
                              void* d_out, int out_size, void* d_ws, size_t ws_size,
                              hipStream_t stream) {
    const float* x = (const float*)d_in[0];
    const float* W = (const float*)d_in[1];
    float* out     = (float*)d_out;

    // output layout (flat concat, everything fp32):
    float* dw      = out;            // [32768,2] dispatch_weights
    float* eidx    = out + 65536;    // [32768,2] expert_indices (as float)
    float* logits  = out + 131072;   // [32768,8] router_logits
    float* scalars = out + 393216;   // lbl, ent_loss, num_dropped, usage[8]
    float* ws      = (float*)d_ws;   // [2048,17] per-wave partials

    fused_kernel<<<512, 256, 0, stream>>>(x, W, logits, dw, eidx, ws);
    finalize_kernel<<<1, 256, 0, stream>>>(ws, scalars);
}